// Round 1
// baseline (43.163 us; speedup 1.0000x reference)
//
#include <hip/hip_runtime.h>

#define NROWS 65536
#define DDIM 512
#define NUM_CLASSES 1000

// ws[0..999]: per-class squared-distance accumulators
__global__ void CenterLoss_zero_ws(float* __restrict__ ws) {
    int i = threadIdx.x + blockIdx.x * blockDim.x;
    if (i < NUM_CLASSES) ws[i] = 0.0f;
}

// One 64-lane wave per row. Block = 256 threads = 4 waves = 4 rows.
__global__ __launch_bounds__(256) void CenterLoss_accum(
    const float* __restrict__ x,
    const int* __restrict__ labels,
    const float* __restrict__ centers,
    float* __restrict__ ws)
{
    const int wave = threadIdx.x >> 6;   // 0..3
    const int lane = threadIdx.x & 63;
    const int row  = (blockIdx.x << 2) + wave;

    const int lbl = labels[row];

    const float4* __restrict__ xr =
        reinterpret_cast<const float4*>(x + (size_t)row * DDIM);
    const float4* __restrict__ cr =
        reinterpret_cast<const float4*>(centers + (size_t)lbl * DDIM);

    // Row = 512 floats = 128 float4. Lane i reads float4 #i and #(i+64):
    // load 1 covers bytes [0,1024) of the row, load 2 covers [1024,2048) —
    // both fully coalesced across the wave.
    float acc = 0.0f;
#pragma unroll
    for (int k = 0; k < 2; ++k) {
        const float4 xv = xr[lane + 64 * k];
        const float4 cv = cr[lane + 64 * k];
        const float dx = xv.x - cv.x;
        const float dy = xv.y - cv.y;
        const float dz = xv.z - cv.z;
        const float dw = xv.w - cv.w;
        acc += dx * dx + dy * dy + dz * dz + dw * dw;
    }

    // 64-lane butterfly reduce
#pragma unroll
    for (int off = 32; off > 0; off >>= 1)
        acc += __shfl_xor(acc, off, 64);

    if (lane == 0)
        atomicAdd(&ws[lbl], acc);
}

__global__ __launch_bounds__(1024) void CenterLoss_finalize(
    const float* __restrict__ ws, float* __restrict__ out)
{
    __shared__ float s[1024];
    const int t = threadIdx.x;
    s[t] = (t < NUM_CLASSES) ? sqrtf(ws[t]) : 0.0f;
    __syncthreads();
#pragma unroll
    for (int off = 512; off > 0; off >>= 1) {
        if (t < off) s[t] += s[t + off];
        __syncthreads();
    }
    if (t == 0) out[0] = s[0] / (float)NUM_CLASSES;
}

extern "C" void kernel_launch(void* const* d_in, const int* in_sizes, int n_in,
                              void* d_out, int out_size, void* d_ws, size_t ws_size,
                              hipStream_t stream) {
    const float* x       = (const float*)d_in[0];
    const int*   labels  = (const int*)d_in[1];
    const float* centers = (const float*)d_in[2];
    float* out = (float*)d_out;
    float* ws  = (float*)d_ws;

    CenterLoss_zero_ws<<<(NUM_CLASSES + 255) / 256, 256, 0, stream>>>(ws);
    CenterLoss_accum<<<NROWS / 4, 256, 0, stream>>>(x, labels, centers, ws);
    CenterLoss_finalize<<<1, 1024, 0, stream>>>(ws, out);
}